// Round 13
// baseline (989.477 us; speedup 1.0000x reference)
//
#include <hip/hip_runtime.h>

#define Bsz 16384
#define TT 10
#define FF 500
#define H1c 256
#define H2c 100

typedef _Float16 half8 __attribute__((ext_vector_type(8)));
typedef float floatx4 __attribute__((ext_vector_type(4)));

__device__ __forceinline__ float sigm(float x) { return 1.0f / (1.0f + __expf(-x)); }

#define GLOAD16(g, l) __builtin_amdgcn_global_load_lds( \
    (const __attribute__((address_space(1))) void*)(g), \
    (__attribute__((address_space(3))) void*)(l), 16, 0, 0)

// ---------------------------------------------------------------------------
// LSTM weight prep (K=768) for 256-wide N-tiles:
// n' = 256*(U>>6) + 64*((U>>4)&3) + 16*g + (U&15)
// ---------------------------------------------------------------------------
__global__ __launch_bounds__(256)
void prep_lstm_w(const float* __restrict__ Wx, const float* __restrict__ Wh,
                 _Float16* __restrict__ WT)
{
    const int idx = blockIdx.x * 256 + threadIdx.x;   // 1024*768
    const int np = idx / 768, k = idx % 768;
    const int A2 = np >> 8, B2 = (np >> 6) & 3, g = (np >> 4) & 3, u = np & 15;
    const int U = A2 * 64 + B2 * 16 + u;
    const int col = g * 256 + U;
    float v = 0.f;
    if (k < 512) { if (k < FF) v = Wx[(size_t)k * 1024 + col]; }
    else v = Wh[(size_t)(k - 512) * 1024 + col];
    WT[idx] = (_Float16)v;
}

// ---------------------------------------------------------------------------
// GRU weight prep: n' = 96*(U>>5)+48*((U>>4)&1)+16*g+(U&15), U in [0,128).
// ---------------------------------------------------------------------------
__global__ __launch_bounds__(256)
void prep_gru_w(const float* __restrict__ Wxg, const float* __restrict__ Whg,
                _Float16* __restrict__ WT)
{
    const int idx = blockIdx.x * 256 + threadIdx.x;   // 384*384
    if (idx >= 384 * 384) return;
    const int np = idx / 384, k = idx % 384;
    const int nb = np / 96, rem = np % 96;
    const int wxx = rem / 48, g = (rem % 48) / 16, u = rem & 15;
    const int U = nb * 32 + wxx * 16 + u;
    float v = 0.f;
    if (U < H2c) {
        if (k < 256) v = Wxg[(size_t)k * 300 + g * H2c + U];
        else if (k - 256 < H2c) v = Whg[(size_t)(k - 256) * 300 + g * H2c + U];
    }
    WT[idx] = (_Float16)v;
}

// ---------------------------------------------------------------------------
// LSTM tile body: 256x256 tile, 8 waves, BK=64, dbuf LDS, r8 schedule.
// x K-phases (kb<512) read noise fp32 DIRECTLY: reg-stage 8 dwordx4 at tile
// start (latency hides under the 64 MFMAs), cvt->fp16, swizzled ds_write
// into the staging buffer (write swizzle c^=(row&7) mirrors the gload/read
// involution). h K-phases and B stay global_load_lds. Panel-affinity map:
// XCD (bid&7) owns weight panel nb=xcd>>1 (L2-resident across steps).
// ---------------------------------------------------------------------------
__device__ __forceinline__
void lstm_tile(int bid, const float* __restrict__ noise, int t,
               const _Float16* __restrict__ WT,
               const float* __restrict__ bias,
               const _Float16* __restrict__ h_prev, const float* __restrict__ c_prev,
               _Float16* __restrict__ h_out, float* __restrict__ c_out,
               int first, _Float16* smem)
{
    _Float16* As = smem;
    _Float16* Bs = smem + 32768;

    const int tid = threadIdx.x;
    const int lane = tid & 63;
    const int w = tid >> 6;
    const int wy = w >> 2, wx = w & 3;
    const int xcd = bid & 7;
    const int nb = xcd >> 1;
    const int row0 = (((xcd & 1) << 5) + (bid >> 3)) * 256;

    const int fr = lane & 15;
    const int l4 = lane >> 4;
    const int sr8 = lane >> 3;
    const int qsrc = (((lane & 7) ^ (sr8 & 7)) << 3);

    const int arow = tid >> 1;          // x-staging: thread owns half-row
    const int kh = (tid & 1) * 32;      // k-offset within BK=64 tile

    floatx4 acc[8][4];
    #pragma unroll
    for (int a = 0; a < 8; ++a)
        #pragma unroll
        for (int b = 0; b < 4; ++b) acc[a][b] = (floatx4){0.f, 0.f, 0.f, 0.f};

    const int nkt = first ? 8 : 12;

    // ---- prologue: stage tile 0 (always x-phase; k<64 all valid) ----
    {
        #pragma unroll
        for (int q = 0; q < 4; ++q) {
            const int r = q * 64 + w * 8;
            GLOAD16(WT + (size_t)(nb * 256 + r + sr8) * 768 + qsrc, &Bs[r * 64]);
        }
        const float* srow = noise + (size_t)(row0 + arow) * (TT * FF) + t * FF + kh;
        float4 xv[8];
        #pragma unroll
        for (int j = 0; j < 8; ++j) xv[j] = *(const float4*)(srow + j * 4);
        #pragma unroll
        for (int cj = 0; cj < 4; ++cj) {
            half8 hv;
            hv[0] = (_Float16)xv[2 * cj].x;     hv[1] = (_Float16)xv[2 * cj].y;
            hv[2] = (_Float16)xv[2 * cj].z;     hv[3] = (_Float16)xv[2 * cj].w;
            hv[4] = (_Float16)xv[2 * cj + 1].x; hv[5] = (_Float16)xv[2 * cj + 1].y;
            hv[6] = (_Float16)xv[2 * cj + 1].z; hv[7] = (_Float16)xv[2 * cj + 1].w;
            const int c = (tid & 1) * 4 + cj;
            *(half8*)&As[(size_t)arow * 64 + (c ^ (arow & 7)) * 8] = hv;
        }
    }
    __syncthreads();

    for (int T = 0; T < nkt; ++T) {
        const int pbase = (T & 1) * 16384;
        const int sbase = pbase ^ 16384;
        const int kb2 = (T + 1) * 64;
        const bool do_stage = (T + 1 < nkt);
        const bool nx_x = kb2 < 512;

        // issue next x-tile register loads early (latency hides under MFMAs)
        float4 xv[8];
        if (do_stage && nx_x) {
            const float* srow = noise + (size_t)(row0 + arow) * (TT * FF) + t * FF + kb2 + kh;
            #pragma unroll
            for (int j = 0; j < 8; ++j) {
                if (kb2 + kh + j * 4 + 3 < FF) xv[j] = *(const float4*)(srow + j * 4);
                else xv[j] = make_float4(0.f, 0.f, 0.f, 0.f);
            }
        }

        #pragma unroll
        for (int q = 0; q < 4; ++q) {
            const int mh = q >> 1, nh = q & 1;
            half8 af[4][2], bf[2][2];
            #pragma unroll
            for (int j = 0; j < 4; ++j) {
                const int row = wy * 128 + (mh * 4 + j) * 16 + fr;
                #pragma unroll
                for (int ks = 0; ks < 2; ++ks) {
                    const int ch = (ks * 4 + l4) ^ (fr & 7);
                    af[j][ks] = *(const half8*)&As[pbase + row * 64 + ch * 8];
                }
            }
            #pragma unroll
            for (int jn = 0; jn < 2; ++jn) {
                const int row = wx * 64 + (nh * 2 + jn) * 16 + fr;
                #pragma unroll
                for (int ks = 0; ks < 2; ++ks) {
                    const int ch = (ks * 4 + l4) ^ (fr & 7);
                    bf[jn][ks] = *(const half8*)&Bs[pbase + row * 64 + ch * 8];
                }
            }
            if (do_stage) {
                const int r = q * 64 + w * 8;
                if (!nx_x)
                    GLOAD16(h_prev + (size_t)(row0 + r + sr8) * 256 + (kb2 - 512) + qsrc, &As[sbase + r * 64]);
                GLOAD16(WT + (size_t)(nb * 256 + r + sr8) * 768 + kb2 + qsrc, &Bs[sbase + r * 64]);
            }
            __builtin_amdgcn_s_setprio(1);
            #pragma unroll
            for (int ks = 0; ks < 2; ++ks)
                #pragma unroll
                for (int j = 0; j < 4; ++j)
                    #pragma unroll
                    for (int jn = 0; jn < 2; ++jn)
                        acc[mh * 4 + j][nh * 2 + jn] = __builtin_amdgcn_mfma_f32_16x16x32_f16(
                            af[j][ks], bf[jn][ks], acc[mh * 4 + j][nh * 2 + jn], 0, 0, 0);
            __builtin_amdgcn_s_setprio(0);
            __builtin_amdgcn_sched_barrier(0);
        }

        // cvt + swizzled write of the next x-tile (compiler inserts vmcnt waits)
        if (do_stage && nx_x) {
            #pragma unroll
            for (int cj = 0; cj < 4; ++cj) {
                half8 hv;
                hv[0] = (_Float16)xv[2 * cj].x;     hv[1] = (_Float16)xv[2 * cj].y;
                hv[2] = (_Float16)xv[2 * cj].z;     hv[3] = (_Float16)xv[2 * cj].w;
                hv[4] = (_Float16)xv[2 * cj + 1].x; hv[5] = (_Float16)xv[2 * cj + 1].y;
                hv[6] = (_Float16)xv[2 * cj + 1].z; hv[7] = (_Float16)xv[2 * cj + 1].w;
                const int c = (tid & 1) * 4 + cj;
                *(half8*)&As[sbase + (size_t)arow * 64 + (c ^ (arow & 7)) * 8] = hv;
            }
        }
        __syncthreads();
    }

    const int U = nb * 64 + wx * 16 + fr;
    const float bi = bias[0 * 256 + U];
    const float bff = bias[1 * 256 + U];
    const float bg = bias[2 * 256 + U];
    const float bo = bias[3 * 256 + U];
    const int rbase = row0 + wy * 128 + l4 * 4;
    #pragma unroll
    for (int mi = 0; mi < 8; ++mi) {
        #pragma unroll
        for (int r = 0; r < 4; ++r) {
            const int row = rbase + mi * 16 + r;
            const float cp = first ? 0.f : c_prev[(size_t)row * 256 + U];
            const float zi = acc[mi][0][r] + bi;
            const float zf = acc[mi][1][r] + bff;
            const float zg = acc[mi][2][r] + bg;
            const float zo = acc[mi][3][r] + bo;
            const float ig = sigm(zi), fg = sigm(zf), og = sigm(zo);
            const float gg = fmaxf(zg, 0.f);
            const float cv = fg * cp + ig * gg;
            const float hv = og * fmaxf(cv, 0.f);
            c_out[(size_t)row * 256 + U] = cv;
            h_out[(size_t)row * 256 + U] = (_Float16)hv;
        }
    }
}

// ---------------------------------------------------------------------------
// GRU tile body (r11-proven): 512 threads, 64 rows x 384 cols, BK=64,
// K=384 (256 h | 128 g16). g-state fp16-only.
// ---------------------------------------------------------------------------
__device__ __forceinline__
void gru_tile(int bid, int first,
              const _Float16* __restrict__ h_r, const _Float16* __restrict__ g16_r,
              const _Float16* __restrict__ WTg,
              const float* __restrict__ b_in, const float* __restrict__ b_rec,
              _Float16* __restrict__ g16_w,
              _Float16* As, _Float16* Bs)
{
    const int tid = threadIdx.x;
    const int lane = tid & 63;
    const int w = tid >> 6;
    const int wq = w >> 2;
    const int wn = w & 3;
    const int rb0 = bid * 64;
    const int fr = lane & 15;
    const int l4 = lane >> 4;
    const int sr8 = lane >> 3;
    const int qsrc = (((lane & 7) ^ sr8) << 3);

    floatx4 accA[2][6], accB[2][6];
    #pragma unroll
    for (int a = 0; a < 2; ++a)
        #pragma unroll
        for (int b = 0; b < 6; ++b) {
            accA[a][b] = (floatx4){0.f, 0.f, 0.f, 0.f};
            accB[a][b] = (floatx4){0.f, 0.f, 0.f, 0.f};
        }

    const int nkt = first ? 4 : 6;
    for (int kt = 0; kt < nkt; ++kt) {
        const int kb = kt * 64;
        {
            const int r = w * 8;
            if (kt < 4)
                GLOAD16(h_r + (size_t)(rb0 + r + sr8) * 256 + kb + qsrc, &As[r * 64]);
            else
                GLOAD16(g16_r + (size_t)(rb0 + r + sr8) * 128 + (kb - 256) + qsrc, &As[r * 64]);
        }
        #pragma unroll
        for (int q = 0; q < 6; ++q) {
            const int r = q * 64 + w * 8;
            GLOAD16(WTg + (size_t)(r + sr8) * 384 + kb + qsrc, &Bs[r * 64]);
        }
        __syncthreads();
        #pragma unroll
        for (int ks = 0; ks < 2; ++ks) {
            half8 af[2], bf[6];
            const int ch0 = (ks * 4 + l4) ^ (fr & 7);
            #pragma unroll
            for (int mf = 0; mf < 2; ++mf) {
                const int row = wq * 32 + mf * 16 + fr;
                af[mf] = *(const half8*)&As[row * 64 + ch0 * 8];
            }
            #pragma unroll
            for (int nf = 0; nf < 6; ++nf) {
                const int row = wn * 96 + nf * 16 + fr;
                bf[nf] = *(const half8*)&Bs[row * 64 + ch0 * 8];
            }
            if (kt < 4) {
                #pragma unroll
                for (int mf = 0; mf < 2; ++mf)
                    #pragma unroll
                    for (int nf = 0; nf < 6; ++nf)
                        accA[mf][nf] = __builtin_amdgcn_mfma_f32_16x16x32_f16(af[mf], bf[nf], accA[mf][nf], 0, 0, 0);
            } else {
                #pragma unroll
                for (int mf = 0; mf < 2; ++mf)
                    #pragma unroll
                    for (int nf = 0; nf < 6; ++nf)
                        accB[mf][nf] = __builtin_amdgcn_mfma_f32_16x16x32_f16(af[mf], bf[nf], accB[mf][nf], 0, 0, 0);
            }
        }
        __syncthreads();
    }

    #pragma unroll
    for (int mf = 0; mf < 2; ++mf) {
        #pragma unroll
        for (int wxx = 0; wxx < 2; ++wxx) {
            const int U = wn * 32 + wxx * 16 + fr;
            const bool uv = U < H2c;
            const float bzi = uv ? b_in[U] : 0.f;
            const float bri = uv ? b_in[H2c + U] : 0.f;
            const float bhi = uv ? b_in[2 * H2c + U] : 0.f;
            const float bzr = uv ? b_rec[U] : 0.f;
            const float brr = uv ? b_rec[H2c + U] : 0.f;
            const float bhr = uv ? b_rec[2 * H2c + U] : 0.f;
            const int nf0 = wxx * 3;
            #pragma unroll
            for (int r = 0; r < 4; ++r) {
                const int row = rb0 + wq * 32 + mf * 16 + l4 * 4 + r;
                const float gp = (!first && uv) ? (float)g16_r[(size_t)row * 128 + U] : 0.f;
                const float mxz = accA[mf][nf0 + 0][r] + bzi;
                const float mxr = accA[mf][nf0 + 1][r] + bri;
                const float mxh = accA[mf][nf0 + 2][r] + bhi;
                const float mhz = accB[mf][nf0 + 0][r] + bzr;
                const float mhr = accB[mf][nf0 + 1][r] + brr;
                const float mhh = accB[mf][nf0 + 2][r] + bhr;
                const float z = sigm(mxz + mhz);
                const float rr = sigm(mxr + mhr);
                const float hc = fmaxf(mxh + rr * mhh, 0.f);
                const float g = z * gp + (1.f - z) * hc;
                g16_w[(size_t)row * 128 + U] = uv ? (_Float16)g : (_Float16)0.f;
            }
        }
    }
}

// ---------------------------------------------------------------------------
// Dense body: rows [bid*64, +64), out = relu(g16 @ Wd + bd).
// ---------------------------------------------------------------------------
__device__ __forceinline__
void dense_tile(int bid, const _Float16* __restrict__ hg, const float* __restrict__ Wd,
                const float* __restrict__ bd, float* __restrict__ out)
{
    const int tid = threadIdx.x;
    if (tid < 64) {
        const int row = bid * 64 + tid;
        float acc[TT];
        #pragma unroll
        for (int j = 0; j < TT; ++j) acc[j] = 0.f;
        const _Float16* gr = hg + (size_t)row * 128;
        for (int k = 0; k < H2c; ++k) {
            const float xv = (float)gr[k];
            #pragma unroll
            for (int j = 0; j < TT; ++j) acc[j] += xv * Wd[k * TT + j];
        }
        #pragma unroll
        for (int j = 0; j < TT; ++j)
            out[(size_t)row * TT + j] = fmaxf(acc[j] + bd[j], 0.f);
    }
}

// ---------------------------------------------------------------------------
// Per-step fused dispatch: LSTM(t) tile (x direct from noise fp32) then
// (t>=1) the 64-row GRU(t-1) slice. Inter-step ordering from the stream.
// ---------------------------------------------------------------------------
__global__ __launch_bounds__(512, 2)
void step_fused(const float* __restrict__ noise, int t,
                const _Float16* __restrict__ WTl,
                const float* __restrict__ b_l,
                const _Float16* __restrict__ h_prev, const float* __restrict__ c_prev,
                _Float16* __restrict__ h_out, float* __restrict__ c_out,
                const _Float16* __restrict__ WTg,
                const float* __restrict__ b_in, const float* __restrict__ b_rec,
                const _Float16* __restrict__ g16_r, _Float16* __restrict__ g16_w,
                int lstm_first, int gru_on, int gru_first)
{
    extern __shared__ _Float16 smem[];
    const int bid = blockIdx.x;
    lstm_tile(bid, noise, t, WTl, b_l, h_prev, c_prev, h_out, c_out, lstm_first, smem);
    if (gru_on)
        gru_tile(bid, gru_first, h_prev, g16_r, WTg, b_in, b_rec, g16_w,
                 smem, smem + 32768);
}

// ---------------------------------------------------------------------------
// Tail: GRU(9) then dense for the same 64 rows (block-local dependency).
// ---------------------------------------------------------------------------
__global__ __launch_bounds__(512, 2)
void gru_dense_tail(const _Float16* __restrict__ h_r, const _Float16* __restrict__ g16_r,
                    const _Float16* __restrict__ WTg,
                    const float* __restrict__ b_in, const float* __restrict__ b_rec,
                    _Float16* __restrict__ g16_w,
                    const float* __restrict__ Wd, const float* __restrict__ bd,
                    float* __restrict__ out)
{
    __shared__ _Float16 smem[28672];
    gru_tile(blockIdx.x, 0, h_r, g16_r, WTg, b_in, b_rec, g16_w,
             smem, smem + 4096);
    __syncthreads();
    dense_tile(blockIdx.x, g16_w, Wd, bd, out);
}

// ---------------------------------------------------------------------------
extern "C" void kernel_launch(void* const* d_in, const int* in_sizes, int n_in,
                              void* d_out, int out_size, void* d_ws, size_t ws_size,
                              hipStream_t stream)
{
    const float* noise  = (const float*)d_in[0];
    const float* Wx_l   = (const float*)d_in[1];
    const float* Wh_l   = (const float*)d_in[2];
    const float* b_l    = (const float*)d_in[3];
    const float* Wx_g   = (const float*)d_in[4];
    const float* Wh_g   = (const float*)d_in[5];
    const float* b_in   = (const float*)d_in[6];
    const float* b_rec  = (const float*)d_in[7];
    const float* Wd     = (const float*)d_in[8];
    const float* bd     = (const float*)d_in[9];
    float* outf = (float*)d_out;

    char* p = (char*)d_ws;
    auto alloc = [&](size_t bytes) {
        char* r = p;
        p += (bytes + 255) & ~(size_t)255;
        return r;
    };
    _Float16* WTl  = (_Float16*)alloc((size_t)1024 * 768 * 2);
    _Float16* WTg  = (_Float16*)alloc((size_t)384 * 384 * 2);
    _Float16* h16A = (_Float16*)alloc((size_t)Bsz * 256 * 2);
    _Float16* h16B = (_Float16*)alloc((size_t)Bsz * 256 * 2);
    float*    cA   = (float*)alloc((size_t)Bsz * 256 * 4);
    float*    cB   = (float*)alloc((size_t)Bsz * 256 * 4);
    _Float16* g16A = (_Float16*)alloc((size_t)Bsz * 128 * 2);
    _Float16* g16B = (_Float16*)alloc((size_t)Bsz * 128 * 2);

    (void)hipFuncSetAttribute((const void*)step_fused,
                              hipFuncAttributeMaxDynamicSharedMemorySize, 131072);

    prep_lstm_w<<<1024 * 768 / 256, 256, 0, stream>>>(Wx_l, Wh_l, WTl);
    prep_gru_w<<<(384 * 384 + 255) / 256, 256, 0, stream>>>(Wx_g, Wh_g, WTg);

    _Float16* hb[2] = {h16A, h16B};   // h(s) in hb[s&1]
    float*    cb[2] = {cA, cB};
    _Float16* gh[2] = {g16A, g16B};   // g(tau) in gh[tau&1]

    for (int t = 0; t < TT; ++t) {
        const int wi = t & 1, ri = (t + 1) & 1;
        // GRU(t-1): reads h(t-1)=hb[ri], g(t-2)=gh[wi]; writes g(t-1)=gh[ri].
        step_fused<<<256, 512, 131072, stream>>>(
            noise, t, WTl, b_l,
            hb[ri], cb[ri], hb[wi], cb[wi],
            WTg, b_in, b_rec, gh[wi], gh[ri],
            t == 0 ? 1 : 0, t >= 1 ? 1 : 0, t == 1 ? 1 : 0);
    }
    // GRU(9): reads h(9)=hb[1], g(8)=gh[0]; writes g(9)=gh[1]; then dense.
    gru_dense_tail<<<256, 512, 0, stream>>>(hb[1], gh[0], WTg, b_in, b_rec,
                                            gh[1], Wd, bd, outf);
}

// Round 14
// 569.377 us; speedup vs baseline: 1.7378x; 1.7378x over previous
//
#include <hip/hip_runtime.h>

#define Bsz 16384
#define TT 10
#define FF 500
#define H1c 256
#define H2c 100

typedef _Float16 half8 __attribute__((ext_vector_type(8)));
typedef float floatx4 __attribute__((ext_vector_type(4)));

__device__ __forceinline__ float sigm(float x) { return 1.0f / (1.0f + __expf(-x)); }

#define GLOAD16(g, l) __builtin_amdgcn_global_load_lds( \
    (const __attribute__((address_space(1))) void*)(g), \
    (__attribute__((address_space(3))) void*)(l), 16, 0, 0)

// ---------------------------------------------------------------------------
// Convert ALL noise fp32 -> xc fp16 once, into t-major planes:
// xc[(t*Bsz + b)*512 + k], 500->512 zero pad. (85% HBM peak, at floor.)
// ---------------------------------------------------------------------------
__global__ __launch_bounds__(256)
void conv_all(const float* __restrict__ noise, _Float16* __restrict__ xc)
{
    const int idx = blockIdx.x * 256 + threadIdx.x;
    const int rb = idx >> 6;           // b*10 + t (noise row)
    const int kc = (idx & 63) << 3;
    const int b = rb / 10;
    const int t = rb - b * 10;
    const float* src = noise + (size_t)rb * FF + kc;
    half8 v;
    if (kc + 8 <= FF) {
        float4 u0 = *(const float4*)src;
        float4 u1 = *(const float4*)(src + 4);
        v[0] = (_Float16)u0.x; v[1] = (_Float16)u0.y; v[2] = (_Float16)u0.z; v[3] = (_Float16)u0.w;
        v[4] = (_Float16)u1.x; v[5] = (_Float16)u1.y; v[6] = (_Float16)u1.z; v[7] = (_Float16)u1.w;
    } else {
        #pragma unroll
        for (int j = 0; j < 8; ++j)
            v[j] = (kc + j < FF) ? (_Float16)src[j] : (_Float16)0.f;
    }
    *(half8*)(xc + ((size_t)t * Bsz + b) * 512 + kc) = v;
}

// ---------------------------------------------------------------------------
// LSTM weight prep (K=768) for 256-wide N-tiles:
// n' = 256*(U>>6) + 64*((U>>4)&3) + 16*g + (U&15)
// ---------------------------------------------------------------------------
__global__ __launch_bounds__(256)
void prep_lstm_w(const float* __restrict__ Wx, const float* __restrict__ Wh,
                 _Float16* __restrict__ WT)
{
    const int idx = blockIdx.x * 256 + threadIdx.x;   // 1024*768
    const int np = idx / 768, k = idx % 768;
    const int A2 = np >> 8, B2 = (np >> 6) & 3, g = (np >> 4) & 3, u = np & 15;
    const int U = A2 * 64 + B2 * 16 + u;
    const int col = g * 256 + U;
    float v = 0.f;
    if (k < 512) { if (k < FF) v = Wx[(size_t)k * 1024 + col]; }
    else v = Wh[(size_t)(k - 512) * 1024 + col];
    WT[idx] = (_Float16)v;
}

// ---------------------------------------------------------------------------
// GRU weight prep: n' = 96*(U>>5)+48*((U>>4)&1)+16*g+(U&15), U in [0,128).
// ---------------------------------------------------------------------------
__global__ __launch_bounds__(256)
void prep_gru_w(const float* __restrict__ Wxg, const float* __restrict__ Whg,
                _Float16* __restrict__ WT)
{
    const int idx = blockIdx.x * 256 + threadIdx.x;   // 384*384
    if (idx >= 384 * 384) return;
    const int np = idx / 384, k = idx % 384;
    const int nb = np / 96, rem = np % 96;
    const int wxx = rem / 48, g = (rem % 48) / 16, u = rem & 15;
    const int U = nb * 32 + wxx * 16 + u;
    float v = 0.f;
    if (U < H2c) {
        if (k < 256) v = Wxg[(size_t)k * 300 + g * H2c + U];
        else if (k - 256 < H2c) v = Whg[(size_t)(k - 256) * 300 + g * H2c + U];
    }
    WT[idx] = (_Float16)v;
}

// ---------------------------------------------------------------------------
// LSTM tile body: 256x256 tile, 8 waves, BK=64, dbuf LDS, XOR chunk swizzle.
// SERPENTINE quadrant order (0,0)->(0,1)->(1,1)->(1,0): af loaded once per
// mh-half, bf held across the shared-nh edge -> 28 ds_read_b128 per
// wave-Ktile (was 48; -42% LDS read traffic, the diagnosed bottleneck).
// Panel-affinity map: XCD (bid&7) owns weight panel nb=xcd>>1.
// ---------------------------------------------------------------------------
__device__ __forceinline__
void lstm_tile(int bid, const _Float16* __restrict__ xct, const _Float16* __restrict__ WT,
               const float* __restrict__ bias,
               const _Float16* __restrict__ h_prev, const float* __restrict__ c_prev,
               _Float16* __restrict__ h_out, float* __restrict__ c_out,
               int first, _Float16* smem)
{
    _Float16* As = smem;
    _Float16* Bs = smem + 32768;

    const int tid = threadIdx.x;
    const int lane = tid & 63;
    const int w = tid >> 6;
    const int wy = w >> 2, wx = w & 3;
    const int xcd = bid & 7;
    const int nb = xcd >> 1;
    const int row0 = (((xcd & 1) << 5) + (bid >> 3)) * 256;

    const int fr = lane & 15;
    const int l4 = lane >> 4;
    const int sr8 = lane >> 3;
    const int qsrc = (((lane & 7) ^ (sr8 & 7)) << 3);

    floatx4 acc[8][4];
    #pragma unroll
    for (int a = 0; a < 8; ++a)
        #pragma unroll
        for (int b = 0; b < 4; ++b) acc[a][b] = (floatx4){0.f, 0.f, 0.f, 0.f};

    const int nkt = first ? 8 : 12;

    #pragma unroll
    for (int q = 0; q < 4; ++q) {
        const int r = q * 64 + w * 8;
        GLOAD16(xct + (size_t)(row0 + r + sr8) * 512 + qsrc, &As[r * 64]);
        GLOAD16(WT + (size_t)(nb * 256 + r + sr8) * 768 + qsrc, &Bs[r * 64]);
    }
    __syncthreads();

    for (int T = 0; T < nkt; ++T) {
        const int pbase = (T & 1) * 16384;
        const int sbase = pbase ^ 16384;
        const int kb2 = (T + 1) * 64;
        const bool do_stage = (T + 1 < nkt);
        const bool from_x = kb2 < 512;

        half8 af[4][2], bf[2][2];

        auto LOAD_AF = [&](int mh) {
            #pragma unroll
            for (int j = 0; j < 4; ++j) {
                const int row = wy * 128 + (mh * 4 + j) * 16 + fr;
                #pragma unroll
                for (int ks = 0; ks < 2; ++ks) {
                    const int ch = (ks * 4 + l4) ^ (fr & 7);
                    af[j][ks] = *(const half8*)&As[pbase + row * 64 + ch * 8];
                }
            }
        };
        auto LOAD_BF = [&](int nh) {
            #pragma unroll
            for (int jn = 0; jn < 2; ++jn) {
                const int row = wx * 64 + (nh * 2 + jn) * 16 + fr;
                #pragma unroll
                for (int ks = 0; ks < 2; ++ks) {
                    const int ch = (ks * 4 + l4) ^ (fr & 7);
                    bf[jn][ks] = *(const half8*)&Bs[pbase + row * 64 + ch * 8];
                }
            }
        };
        auto STAGE_Q = [&](int q) {
            const int r = q * 64 + w * 8;
            if (from_x)
                GLOAD16(xct + (size_t)(row0 + r + sr8) * 512 + kb2 + qsrc, &As[sbase + r * 64]);
            else
                GLOAD16(h_prev + (size_t)(row0 + r + sr8) * 256 + (kb2 - 512) + qsrc, &As[sbase + r * 64]);
            GLOAD16(WT + (size_t)(nb * 256 + r + sr8) * 768 + kb2 + qsrc, &Bs[sbase + r * 64]);
        };
        auto MFMA_Q = [&](int mh, int nh) {
            __builtin_amdgcn_s_setprio(1);
            #pragma unroll
            for (int ks = 0; ks < 2; ++ks)
                #pragma unroll
                for (int j = 0; j < 4; ++j)
                    #pragma unroll
                    for (int jn = 0; jn < 2; ++jn)
                        acc[mh * 4 + j][nh * 2 + jn] = __builtin_amdgcn_mfma_f32_16x16x32_f16(
                            af[j][ks], bf[jn][ks], acc[mh * 4 + j][nh * 2 + jn], 0, 0, 0);
            __builtin_amdgcn_s_setprio(0);
            __builtin_amdgcn_sched_barrier(0);
        };

        LOAD_AF(0); LOAD_BF(0); if (do_stage) STAGE_Q(0); MFMA_Q(0, 0);
        LOAD_BF(1);             if (do_stage) STAGE_Q(1); MFMA_Q(0, 1);
        LOAD_AF(1);             if (do_stage) STAGE_Q(2); MFMA_Q(1, 1);
        LOAD_BF(0);             if (do_stage) STAGE_Q(3); MFMA_Q(1, 0);
        __syncthreads();
    }

    const int U = nb * 64 + wx * 16 + fr;
    const float bi = bias[0 * 256 + U];
    const float bff = bias[1 * 256 + U];
    const float bg = bias[2 * 256 + U];
    const float bo = bias[3 * 256 + U];
    const int rbase = row0 + wy * 128 + l4 * 4;
    #pragma unroll
    for (int mi = 0; mi < 8; ++mi) {
        #pragma unroll
        for (int r = 0; r < 4; ++r) {
            const int row = rbase + mi * 16 + r;
            const float cp = first ? 0.f : c_prev[(size_t)row * 256 + U];
            const float zi = acc[mi][0][r] + bi;
            const float zf = acc[mi][1][r] + bff;
            const float zg = acc[mi][2][r] + bg;
            const float zo = acc[mi][3][r] + bo;
            const float ig = sigm(zi), fg = sigm(zf), og = sigm(zo);
            const float gg = fmaxf(zg, 0.f);
            const float cv = fg * cp + ig * gg;
            const float hv = og * fmaxf(cv, 0.f);
            c_out[(size_t)row * 256 + U] = cv;
            h_out[(size_t)row * 256 + U] = (_Float16)hv;
        }
    }
}

// ---------------------------------------------------------------------------
// GRU tile body (r11-proven): 512 threads, 64 rows x 384 cols, BK=64,
// K=384 (256 h | 128 g16). g-state fp16-only.
// ---------------------------------------------------------------------------
__device__ __forceinline__
void gru_tile(int bid, int first,
              const _Float16* __restrict__ h_r, const _Float16* __restrict__ g16_r,
              const _Float16* __restrict__ WTg,
              const float* __restrict__ b_in, const float* __restrict__ b_rec,
              _Float16* __restrict__ g16_w,
              _Float16* As, _Float16* Bs)
{
    const int tid = threadIdx.x;
    const int lane = tid & 63;
    const int w = tid >> 6;
    const int wq = w >> 2;
    const int wn = w & 3;
    const int rb0 = bid * 64;
    const int fr = lane & 15;
    const int l4 = lane >> 4;
    const int sr8 = lane >> 3;
    const int qsrc = (((lane & 7) ^ sr8) << 3);

    floatx4 accA[2][6], accB[2][6];
    #pragma unroll
    for (int a = 0; a < 2; ++a)
        #pragma unroll
        for (int b = 0; b < 6; ++b) {
            accA[a][b] = (floatx4){0.f, 0.f, 0.f, 0.f};
            accB[a][b] = (floatx4){0.f, 0.f, 0.f, 0.f};
        }

    const int nkt = first ? 4 : 6;
    for (int kt = 0; kt < nkt; ++kt) {
        const int kb = kt * 64;
        {
            const int r = w * 8;
            if (kt < 4)
                GLOAD16(h_r + (size_t)(rb0 + r + sr8) * 256 + kb + qsrc, &As[r * 64]);
            else
                GLOAD16(g16_r + (size_t)(rb0 + r + sr8) * 128 + (kb - 256) + qsrc, &As[r * 64]);
        }
        #pragma unroll
        for (int q = 0; q < 6; ++q) {
            const int r = q * 64 + w * 8;
            GLOAD16(WTg + (size_t)(r + sr8) * 384 + kb + qsrc, &Bs[r * 64]);
        }
        __syncthreads();
        #pragma unroll
        for (int ks = 0; ks < 2; ++ks) {
            half8 af[2], bf[6];
            const int ch0 = (ks * 4 + l4) ^ (fr & 7);
            #pragma unroll
            for (int mf = 0; mf < 2; ++mf) {
                const int row = wq * 32 + mf * 16 + fr;
                af[mf] = *(const half8*)&As[row * 64 + ch0 * 8];
            }
            #pragma unroll
            for (int nf = 0; nf < 6; ++nf) {
                const int row = wn * 96 + nf * 16 + fr;
                bf[nf] = *(const half8*)&Bs[row * 64 + ch0 * 8];
            }
            if (kt < 4) {
                #pragma unroll
                for (int mf = 0; mf < 2; ++mf)
                    #pragma unroll
                    for (int nf = 0; nf < 6; ++nf)
                        accA[mf][nf] = __builtin_amdgcn_mfma_f32_16x16x32_f16(af[mf], bf[nf], accA[mf][nf], 0, 0, 0);
            } else {
                #pragma unroll
                for (int mf = 0; mf < 2; ++mf)
                    #pragma unroll
                    for (int nf = 0; nf < 6; ++nf)
                        accB[mf][nf] = __builtin_amdgcn_mfma_f32_16x16x32_f16(af[mf], bf[nf], accB[mf][nf], 0, 0, 0);
            }
        }
        __syncthreads();
    }

    #pragma unroll
    for (int mf = 0; mf < 2; ++mf) {
        #pragma unroll
        for (int wxx = 0; wxx < 2; ++wxx) {
            const int U = wn * 32 + wxx * 16 + fr;
            const bool uv = U < H2c;
            const float bzi = uv ? b_in[U] : 0.f;
            const float bri = uv ? b_in[H2c + U] : 0.f;
            const float bhi = uv ? b_in[2 * H2c + U] : 0.f;
            const float bzr = uv ? b_rec[U] : 0.f;
            const float brr = uv ? b_rec[H2c + U] : 0.f;
            const float bhr = uv ? b_rec[2 * H2c + U] : 0.f;
            const int nf0 = wxx * 3;
            #pragma unroll
            for (int r = 0; r < 4; ++r) {
                const int row = rb0 + wq * 32 + mf * 16 + l4 * 4 + r;
                const float gp = (!first && uv) ? (float)g16_r[(size_t)row * 128 + U] : 0.f;
                const float mxz = accA[mf][nf0 + 0][r] + bzi;
                const float mxr = accA[mf][nf0 + 1][r] + bri;
                const float mxh = accA[mf][nf0 + 2][r] + bhi;
                const float mhz = accB[mf][nf0 + 0][r] + bzr;
                const float mhr = accB[mf][nf0 + 1][r] + brr;
                const float mhh = accB[mf][nf0 + 2][r] + bhr;
                const float z = sigm(mxz + mhz);
                const float rr = sigm(mxr + mhr);
                const float hc = fmaxf(mxh + rr * mhh, 0.f);
                const float g = z * gp + (1.f - z) * hc;
                g16_w[(size_t)row * 128 + U] = uv ? (_Float16)g : (_Float16)0.f;
            }
        }
    }
}

// ---------------------------------------------------------------------------
// Dense body: rows [bid*64, +64), out = relu(g16 @ Wd + bd).
// ---------------------------------------------------------------------------
__device__ __forceinline__
void dense_tile(int bid, const _Float16* __restrict__ hg, const float* __restrict__ Wd,
                const float* __restrict__ bd, float* __restrict__ out)
{
    const int tid = threadIdx.x;
    if (tid < 64) {
        const int row = bid * 64 + tid;
        float acc[TT];
        #pragma unroll
        for (int j = 0; j < TT; ++j) acc[j] = 0.f;
        const _Float16* gr = hg + (size_t)row * 128;
        for (int k = 0; k < H2c; ++k) {
            const float xv = (float)gr[k];
            #pragma unroll
            for (int j = 0; j < TT; ++j) acc[j] += xv * Wd[k * TT + j];
        }
        #pragma unroll
        for (int j = 0; j < TT; ++j)
            out[(size_t)row * TT + j] = fmaxf(acc[j] + bd[j], 0.f);
    }
}

// ---------------------------------------------------------------------------
// Per-step fused dispatch: LSTM(t) tile then (t>=1) 64-row GRU(t-1) slice.
// ---------------------------------------------------------------------------
__global__ __launch_bounds__(512, 2)
void step_fused(const _Float16* __restrict__ xct, const _Float16* __restrict__ WTl,
                const float* __restrict__ b_l,
                const _Float16* __restrict__ h_prev, const float* __restrict__ c_prev,
                _Float16* __restrict__ h_out, float* __restrict__ c_out,
                const _Float16* __restrict__ WTg,
                const float* __restrict__ b_in, const float* __restrict__ b_rec,
                const _Float16* __restrict__ g16_r, _Float16* __restrict__ g16_w,
                int lstm_first, int gru_on, int gru_first)
{
    extern __shared__ _Float16 smem[];
    const int bid = blockIdx.x;
    lstm_tile(bid, xct, WTl, b_l, h_prev, c_prev, h_out, c_out, lstm_first, smem);
    if (gru_on)
        gru_tile(bid, gru_first, h_prev, g16_r, WTg, b_in, b_rec, g16_w,
                 smem, smem + 32768);
}

// ---------------------------------------------------------------------------
// Tail: GRU(9) then dense for the same 64 rows (block-local dependency).
// ---------------------------------------------------------------------------
__global__ __launch_bounds__(512, 2)
void gru_dense_tail(const _Float16* __restrict__ h_r, const _Float16* __restrict__ g16_r,
                    const _Float16* __restrict__ WTg,
                    const float* __restrict__ b_in, const float* __restrict__ b_rec,
                    _Float16* __restrict__ g16_w,
                    const float* __restrict__ Wd, const float* __restrict__ bd,
                    float* __restrict__ out)
{
    __shared__ _Float16 smem[28672];
    gru_tile(blockIdx.x, 0, h_r, g16_r, WTg, b_in, b_rec, g16_w,
             smem, smem + 4096);
    __syncthreads();
    dense_tile(blockIdx.x, g16_w, Wd, bd, out);
}

// ---------------------------------------------------------------------------
extern "C" void kernel_launch(void* const* d_in, const int* in_sizes, int n_in,
                              void* d_out, int out_size, void* d_ws, size_t ws_size,
                              hipStream_t stream)
{
    const float* noise  = (const float*)d_in[0];
    const float* Wx_l   = (const float*)d_in[1];
    const float* Wh_l   = (const float*)d_in[2];
    const float* b_l    = (const float*)d_in[3];
    const float* Wx_g   = (const float*)d_in[4];
    const float* Wh_g   = (const float*)d_in[5];
    const float* b_in   = (const float*)d_in[6];
    const float* b_rec  = (const float*)d_in[7];
    const float* Wd     = (const float*)d_in[8];
    const float* bd     = (const float*)d_in[9];
    float* outf = (float*)d_out;

    char* p = (char*)d_ws;
    auto alloc = [&](size_t bytes) {
        char* r = p;
        p += (bytes + 255) & ~(size_t)255;
        return r;
    };
    _Float16* WTl  = (_Float16*)alloc((size_t)1024 * 768 * 2);
    _Float16* WTg  = (_Float16*)alloc((size_t)384 * 384 * 2);
    _Float16* xc   = (_Float16*)alloc((size_t)Bsz * TT * 512 * 2);
    _Float16* h16A = (_Float16*)alloc((size_t)Bsz * 256 * 2);
    _Float16* h16B = (_Float16*)alloc((size_t)Bsz * 256 * 2);
    float*    cA   = (float*)alloc((size_t)Bsz * 256 * 4);
    float*    cB   = (float*)alloc((size_t)Bsz * 256 * 4);
    _Float16* g16A = (_Float16*)alloc((size_t)Bsz * 128 * 2);
    _Float16* g16B = (_Float16*)alloc((size_t)Bsz * 128 * 2);

    (void)hipFuncSetAttribute((const void*)step_fused,
                              hipFuncAttributeMaxDynamicSharedMemorySize, 131072);

    conv_all<<<Bsz * TT * 64 / 256, 256, 0, stream>>>(noise, xc);
    prep_lstm_w<<<1024 * 768 / 256, 256, 0, stream>>>(Wx_l, Wh_l, WTl);
    prep_gru_w<<<(384 * 384 + 255) / 256, 256, 0, stream>>>(Wx_g, Wh_g, WTg);

    _Float16* hb[2] = {h16A, h16B};   // h(s) in hb[s&1]
    float*    cb[2] = {cA, cB};
    _Float16* gh[2] = {g16A, g16B};   // g(tau) in gh[tau&1]

    for (int t = 0; t < TT; ++t) {
        const int wi = t & 1, ri = (t + 1) & 1;
        // GRU(t-1): reads h(t-1)=hb[ri], g(t-2)=gh[wi]; writes g(t-1)=gh[ri].
        step_fused<<<256, 512, 131072, stream>>>(
            xc + (size_t)t * Bsz * 512, WTl, b_l,
            hb[ri], cb[ri], hb[wi], cb[wi],
            WTg, b_in, b_rec, gh[wi], gh[ri],
            t == 0 ? 1 : 0, t >= 1 ? 1 : 0, t == 1 ? 1 : 0);
    }
    // GRU(9): reads h(9)=hb[1], g(8)=gh[0]; writes g(9)=gh[1]; then dense.
    gru_dense_tail<<<256, 512, 0, stream>>>(hb[1], gh[0], WTg, b_in, b_rec,
                                            gh[1], Wd, bd, outf);
}

// Round 15
// 559.365 us; speedup vs baseline: 1.7689x; 1.0179x over previous
//
#include <hip/hip_runtime.h>

#define Bsz 16384
#define TT 10
#define FF 500
#define H1c 256
#define H2c 100

typedef _Float16 half8 __attribute__((ext_vector_type(8)));
typedef float floatx4 __attribute__((ext_vector_type(4)));

__device__ __forceinline__ float sigm(float x) { return 1.0f / (1.0f + __expf(-x)); }

#define GLOAD16(g, l) __builtin_amdgcn_global_load_lds( \
    (const __attribute__((address_space(1))) void*)(g), \
    (__attribute__((address_space(3))) void*)(l), 16, 0, 0)

// ---------------------------------------------------------------------------
// Convert ALL noise fp32 -> xc fp16 once, into t-major planes:
// xc[(t*Bsz + b)*512 + k], 500->512 zero pad. (85% HBM peak, at floor.)
// ---------------------------------------------------------------------------
__global__ __launch_bounds__(256)
void conv_all(const float* __restrict__ noise, _Float16* __restrict__ xc)
{
    const int idx = blockIdx.x * 256 + threadIdx.x;
    const int rb = idx >> 6;           // b*10 + t (noise row)
    const int kc = (idx & 63) << 3;
    const int b = rb / 10;
    const int t = rb - b * 10;
    const float* src = noise + (size_t)rb * FF + kc;
    half8 v;
    if (kc + 8 <= FF) {
        float4 u0 = *(const float4*)src;
        float4 u1 = *(const float4*)(src + 4);
        v[0] = (_Float16)u0.x; v[1] = (_Float16)u0.y; v[2] = (_Float16)u0.z; v[3] = (_Float16)u0.w;
        v[4] = (_Float16)u1.x; v[5] = (_Float16)u1.y; v[6] = (_Float16)u1.z; v[7] = (_Float16)u1.w;
    } else {
        #pragma unroll
        for (int j = 0; j < 8; ++j)
            v[j] = (kc + j < FF) ? (_Float16)src[j] : (_Float16)0.f;
    }
    *(half8*)(xc + ((size_t)t * Bsz + b) * 512 + kc) = v;
}

// ---------------------------------------------------------------------------
// LSTM weight prep (K=768) for 256-wide N-tiles:
// n' = 256*(U>>6) + 64*((U>>4)&3) + 16*g + (U&15)
// ---------------------------------------------------------------------------
__global__ __launch_bounds__(256)
void prep_lstm_w(const float* __restrict__ Wx, const float* __restrict__ Wh,
                 _Float16* __restrict__ WT)
{
    const int idx = blockIdx.x * 256 + threadIdx.x;   // 1024*768
    const int np = idx / 768, k = idx % 768;
    const int A2 = np >> 8, B2 = (np >> 6) & 3, g = (np >> 4) & 3, u = np & 15;
    const int U = A2 * 64 + B2 * 16 + u;
    const int col = g * 256 + U;
    float v = 0.f;
    if (k < 512) { if (k < FF) v = Wx[(size_t)k * 1024 + col]; }
    else v = Wh[(size_t)(k - 512) * 1024 + col];
    WT[idx] = (_Float16)v;
}

// ---------------------------------------------------------------------------
// GRU weight prep: n' = 96*(U>>5)+48*((U>>4)&1)+16*g+(U&15), U in [0,128).
// ---------------------------------------------------------------------------
__global__ __launch_bounds__(256)
void prep_gru_w(const float* __restrict__ Wxg, const float* __restrict__ Whg,
                _Float16* __restrict__ WT)
{
    const int idx = blockIdx.x * 256 + threadIdx.x;   // 384*384
    if (idx >= 384 * 384) return;
    const int np = idx / 384, k = idx % 384;
    const int nb = np / 96, rem = np % 96;
    const int wxx = rem / 48, g = (rem % 48) / 16, u = rem & 15;
    const int U = nb * 32 + wxx * 16 + u;
    float v = 0.f;
    if (U < H2c) {
        if (k < 256) v = Wxg[(size_t)k * 300 + g * H2c + U];
        else if (k - 256 < H2c) v = Whg[(size_t)(k - 256) * 300 + g * H2c + U];
    }
    WT[idx] = (_Float16)v;
}

// ---------------------------------------------------------------------------
// LSTM tile body: 256x256 tile, 8 waves, BK=64, dbuf LDS, XOR chunk swizzle,
// serpentine quadrant order. CHANGES vs r14:
//  (1) NO sched_barrier(0) -- let the compiler software-pipeline ds_reads
//      and MFMAs across quadrant phases (m141: the pin costs ~40%).
//  (2) All 8 staging gloads issued in phases 0-1 -> last load has ~2 phases
//      (> HBM latency) before the boundary vmcnt(0) drain (stall ~0).
// Panel-affinity map: XCD (bid&7) owns weight panel nb=xcd>>1.
// ---------------------------------------------------------------------------
__device__ __forceinline__
void lstm_tile(int bid, const _Float16* __restrict__ xct, const _Float16* __restrict__ WT,
               const float* __restrict__ bias,
               const _Float16* __restrict__ h_prev, const float* __restrict__ c_prev,
               _Float16* __restrict__ h_out, float* __restrict__ c_out,
               int first, _Float16* smem)
{
    _Float16* As = smem;
    _Float16* Bs = smem + 32768;

    const int tid = threadIdx.x;
    const int lane = tid & 63;
    const int w = tid >> 6;
    const int wy = w >> 2, wx = w & 3;
    const int xcd = bid & 7;
    const int nb = xcd >> 1;
    const int row0 = (((xcd & 1) << 5) + (bid >> 3)) * 256;

    const int fr = lane & 15;
    const int l4 = lane >> 4;
    const int sr8 = lane >> 3;
    const int qsrc = (((lane & 7) ^ (sr8 & 7)) << 3);

    floatx4 acc[8][4];
    #pragma unroll
    for (int a = 0; a < 8; ++a)
        #pragma unroll
        for (int b = 0; b < 4; ++b) acc[a][b] = (floatx4){0.f, 0.f, 0.f, 0.f};

    const int nkt = first ? 8 : 12;

    #pragma unroll
    for (int q = 0; q < 4; ++q) {
        const int r = q * 64 + w * 8;
        GLOAD16(xct + (size_t)(row0 + r + sr8) * 512 + qsrc, &As[r * 64]);
        GLOAD16(WT + (size_t)(nb * 256 + r + sr8) * 768 + qsrc, &Bs[r * 64]);
    }
    __syncthreads();

    for (int T = 0; T < nkt; ++T) {
        const int pbase = (T & 1) * 16384;
        const int sbase = pbase ^ 16384;
        const int kb2 = (T + 1) * 64;
        const bool do_stage = (T + 1 < nkt);
        const bool from_x = kb2 < 512;

        half8 af[4][2], bf[2][2];

        auto LOAD_AF = [&](int mh) {
            #pragma unroll
            for (int j = 0; j < 4; ++j) {
                const int row = wy * 128 + (mh * 4 + j) * 16 + fr;
                #pragma unroll
                for (int ks = 0; ks < 2; ++ks) {
                    const int ch = (ks * 4 + l4) ^ (fr & 7);
                    af[j][ks] = *(const half8*)&As[pbase + row * 64 + ch * 8];
                }
            }
        };
        auto LOAD_BF = [&](int nh) {
            #pragma unroll
            for (int jn = 0; jn < 2; ++jn) {
                const int row = wx * 64 + (nh * 2 + jn) * 16 + fr;
                #pragma unroll
                for (int ks = 0; ks < 2; ++ks) {
                    const int ch = (ks * 4 + l4) ^ (fr & 7);
                    bf[jn][ks] = *(const half8*)&Bs[pbase + row * 64 + ch * 8];
                }
            }
        };
        auto STAGE_Q = [&](int q) {
            const int r = q * 64 + w * 8;
            if (from_x)
                GLOAD16(xct + (size_t)(row0 + r + sr8) * 512 + kb2 + qsrc, &As[sbase + r * 64]);
            else
                GLOAD16(h_prev + (size_t)(row0 + r + sr8) * 256 + (kb2 - 512) + qsrc, &As[sbase + r * 64]);
            GLOAD16(WT + (size_t)(nb * 256 + r + sr8) * 768 + kb2 + qsrc, &Bs[sbase + r * 64]);
        };
        auto MFMA_Q = [&](int mh, int nh) {
            __builtin_amdgcn_s_setprio(1);
            #pragma unroll
            for (int ks = 0; ks < 2; ++ks)
                #pragma unroll
                for (int j = 0; j < 4; ++j)
                    #pragma unroll
                    for (int jn = 0; jn < 2; ++jn)
                        acc[mh * 4 + j][nh * 2 + jn] = __builtin_amdgcn_mfma_f32_16x16x32_f16(
                            af[j][ks], bf[jn][ks], acc[mh * 4 + j][nh * 2 + jn], 0, 0, 0);
            __builtin_amdgcn_s_setprio(0);
            // NOTE: no sched_barrier(0) -- the compiler may hoist the next
            // quadrant's ds_reads into/above this MFMA cluster.
        };

        // Serpentine: (0,0) -> (0,1) -> (1,1) -> (1,0); all staging in the
        // first two phases so the boundary vmcnt(0) finds the loads landed.
        LOAD_AF(0); LOAD_BF(0);
        if (do_stage) { STAGE_Q(0); STAGE_Q(1); }
        MFMA_Q(0, 0);
        LOAD_BF(1);
        if (do_stage) { STAGE_Q(2); STAGE_Q(3); }
        MFMA_Q(0, 1);
        LOAD_AF(1);
        MFMA_Q(1, 1);
        LOAD_BF(0);
        MFMA_Q(1, 0);
        __syncthreads();
    }

    const int U = nb * 64 + wx * 16 + fr;
    const float bi = bias[0 * 256 + U];
    const float bff = bias[1 * 256 + U];
    const float bg = bias[2 * 256 + U];
    const float bo = bias[3 * 256 + U];
    const int rbase = row0 + wy * 128 + l4 * 4;
    #pragma unroll
    for (int mi = 0; mi < 8; ++mi) {
        #pragma unroll
        for (int r = 0; r < 4; ++r) {
            const int row = rbase + mi * 16 + r;
            const float cp = first ? 0.f : c_prev[(size_t)row * 256 + U];
            const float zi = acc[mi][0][r] + bi;
            const float zf = acc[mi][1][r] + bff;
            const float zg = acc[mi][2][r] + bg;
            const float zo = acc[mi][3][r] + bo;
            const float ig = sigm(zi), fg = sigm(zf), og = sigm(zo);
            const float gg = fmaxf(zg, 0.f);
            const float cv = fg * cp + ig * gg;
            const float hv = og * fmaxf(cv, 0.f);
            c_out[(size_t)row * 256 + U] = cv;
            h_out[(size_t)row * 256 + U] = (_Float16)hv;
        }
    }
}

// ---------------------------------------------------------------------------
// GRU tile body (r11-proven): 512 threads, 64 rows x 384 cols, BK=64,
// K=384 (256 h | 128 g16). g-state fp16-only.
// ---------------------------------------------------------------------------
__device__ __forceinline__
void gru_tile(int bid, int first,
              const _Float16* __restrict__ h_r, const _Float16* __restrict__ g16_r,
              const _Float16* __restrict__ WTg,
              const float* __restrict__ b_in, const float* __restrict__ b_rec,
              _Float16* __restrict__ g16_w,
              _Float16* As, _Float16* Bs)
{
    const int tid = threadIdx.x;
    const int lane = tid & 63;
    const int w = tid >> 6;
    const int wq = w >> 2;
    const int wn = w & 3;
    const int rb0 = bid * 64;
    const int fr = lane & 15;
    const int l4 = lane >> 4;
    const int sr8 = lane >> 3;
    const int qsrc = (((lane & 7) ^ sr8) << 3);

    floatx4 accA[2][6], accB[2][6];
    #pragma unroll
    for (int a = 0; a < 2; ++a)
        #pragma unroll
        for (int b = 0; b < 6; ++b) {
            accA[a][b] = (floatx4){0.f, 0.f, 0.f, 0.f};
            accB[a][b] = (floatx4){0.f, 0.f, 0.f, 0.f};
        }

    const int nkt = first ? 4 : 6;
    for (int kt = 0; kt < nkt; ++kt) {
        const int kb = kt * 64;
        {
            const int r = w * 8;
            if (kt < 4)
                GLOAD16(h_r + (size_t)(rb0 + r + sr8) * 256 + kb + qsrc, &As[r * 64]);
            else
                GLOAD16(g16_r + (size_t)(rb0 + r + sr8) * 128 + (kb - 256) + qsrc, &As[r * 64]);
        }
        #pragma unroll
        for (int q = 0; q < 6; ++q) {
            const int r = q * 64 + w * 8;
            GLOAD16(WTg + (size_t)(r + sr8) * 384 + kb + qsrc, &Bs[r * 64]);
        }
        __syncthreads();
        #pragma unroll
        for (int ks = 0; ks < 2; ++ks) {
            half8 af[2], bf[6];
            const int ch0 = (ks * 4 + l4) ^ (fr & 7);
            #pragma unroll
            for (int mf = 0; mf < 2; ++mf) {
                const int row = wq * 32 + mf * 16 + fr;
                af[mf] = *(const half8*)&As[row * 64 + ch0 * 8];
            }
            #pragma unroll
            for (int nf = 0; nf < 6; ++nf) {
                const int row = wn * 96 + nf * 16 + fr;
                bf[nf] = *(const half8*)&Bs[row * 64 + ch0 * 8];
            }
            if (kt < 4) {
                #pragma unroll
                for (int mf = 0; mf < 2; ++mf)
                    #pragma unroll
                    for (int nf = 0; nf < 6; ++nf)
                        accA[mf][nf] = __builtin_amdgcn_mfma_f32_16x16x32_f16(af[mf], bf[nf], accA[mf][nf], 0, 0, 0);
            } else {
                #pragma unroll
                for (int mf = 0; mf < 2; ++mf)
                    #pragma unroll
                    for (int nf = 0; nf < 6; ++nf)
                        accB[mf][nf] = __builtin_amdgcn_mfma_f32_16x16x32_f16(af[mf], bf[nf], accB[mf][nf], 0, 0, 0);
            }
        }
        __syncthreads();
    }

    #pragma unroll
    for (int mf = 0; mf < 2; ++mf) {
        #pragma unroll
        for (int wxx = 0; wxx < 2; ++wxx) {
            const int U = wn * 32 + wxx * 16 + fr;
            const bool uv = U < H2c;
            const float bzi = uv ? b_in[U] : 0.f;
            const float bri = uv ? b_in[H2c + U] : 0.f;
            const float bhi = uv ? b_in[2 * H2c + U] : 0.f;
            const float bzr = uv ? b_rec[U] : 0.f;
            const float brr = uv ? b_rec[H2c + U] : 0.f;
            const float bhr = uv ? b_rec[2 * H2c + U] : 0.f;
            const int nf0 = wxx * 3;
            #pragma unroll
            for (int r = 0; r < 4; ++r) {
                const int row = rb0 + wq * 32 + mf * 16 + l4 * 4 + r;
                const float gp = (!first && uv) ? (float)g16_r[(size_t)row * 128 + U] : 0.f;
                const float mxz = accA[mf][nf0 + 0][r] + bzi;
                const float mxr = accA[mf][nf0 + 1][r] + bri;
                const float mxh = accA[mf][nf0 + 2][r] + bhi;
                const float mhz = accB[mf][nf0 + 0][r] + bzr;
                const float mhr = accB[mf][nf0 + 1][r] + brr;
                const float mhh = accB[mf][nf0 + 2][r] + bhr;
                const float z = sigm(mxz + mhz);
                const float rr = sigm(mxr + mhr);
                const float hc = fmaxf(mxh + rr * mhh, 0.f);
                const float g = z * gp + (1.f - z) * hc;
                g16_w[(size_t)row * 128 + U] = uv ? (_Float16)g : (_Float16)0.f;
            }
        }
    }
}

// ---------------------------------------------------------------------------
// Dense body: rows [bid*64, +64), out = relu(g16 @ Wd + bd).
// ---------------------------------------------------------------------------
__device__ __forceinline__
void dense_tile(int bid, const _Float16* __restrict__ hg, const float* __restrict__ Wd,
                const float* __restrict__ bd, float* __restrict__ out)
{
    const int tid = threadIdx.x;
    if (tid < 64) {
        const int row = bid * 64 + tid;
        float acc[TT];
        #pragma unroll
        for (int j = 0; j < TT; ++j) acc[j] = 0.f;
        const _Float16* gr = hg + (size_t)row * 128;
        for (int k = 0; k < H2c; ++k) {
            const float xv = (float)gr[k];
            #pragma unroll
            for (int j = 0; j < TT; ++j) acc[j] += xv * Wd[k * TT + j];
        }
        #pragma unroll
        for (int j = 0; j < TT; ++j)
            out[(size_t)row * TT + j] = fmaxf(acc[j] + bd[j], 0.f);
    }
}

// ---------------------------------------------------------------------------
// Per-step fused dispatch: LSTM(t) tile then (t>=1) 64-row GRU(t-1) slice.
// ---------------------------------------------------------------------------
__global__ __launch_bounds__(512, 2)
void step_fused(const _Float16* __restrict__ xct, const _Float16* __restrict__ WTl,
                const float* __restrict__ b_l,
                const _Float16* __restrict__ h_prev, const float* __restrict__ c_prev,
                _Float16* __restrict__ h_out, float* __restrict__ c_out,
                const _Float16* __restrict__ WTg,
                const float* __restrict__ b_in, const float* __restrict__ b_rec,
                const _Float16* __restrict__ g16_r, _Float16* __restrict__ g16_w,
                int lstm_first, int gru_on, int gru_first)
{
    extern __shared__ _Float16 smem[];
    const int bid = blockIdx.x;
    lstm_tile(bid, xct, WTl, b_l, h_prev, c_prev, h_out, c_out, lstm_first, smem);
    if (gru_on)
        gru_tile(bid, gru_first, h_prev, g16_r, WTg, b_in, b_rec, g16_w,
                 smem, smem + 32768);
}

// ---------------------------------------------------------------------------
// Tail: GRU(9) then dense for the same 64 rows (block-local dependency).
// ---------------------------------------------------------------------------
__global__ __launch_bounds__(512, 2)
void gru_dense_tail(const _Float16* __restrict__ h_r, const _Float16* __restrict__ g16_r,
                    const _Float16* __restrict__ WTg,
                    const float* __restrict__ b_in, const float* __restrict__ b_rec,
                    _Float16* __restrict__ g16_w,
                    const float* __restrict__ Wd, const float* __restrict__ bd,
                    float* __restrict__ out)
{
    __shared__ _Float16 smem[28672];
    gru_tile(blockIdx.x, 0, h_r, g16_r, WTg, b_in, b_rec, g16_w,
             smem, smem + 4096);
    __syncthreads();
    dense_tile(blockIdx.x, g16_w, Wd, bd, out);
}

// ---------------------------------------------------------------------------
extern "C" void kernel_launch(void* const* d_in, const int* in_sizes, int n_in,
                              void* d_out, int out_size, void* d_ws, size_t ws_size,
                              hipStream_t stream)
{
    const float* noise  = (const float*)d_in[0];
    const float* Wx_l   = (const float*)d_in[1];
    const float* Wh_l   = (const float*)d_in[2];
    const float* b_l    = (const float*)d_in[3];
    const float* Wx_g   = (const float*)d_in[4];
    const float* Wh_g   = (const float*)d_in[5];
    const float* b_in   = (const float*)d_in[6];
    const float* b_rec  = (const float*)d_in[7];
    const float* Wd     = (const float*)d_in[8];
    const float* bd     = (const float*)d_in[9];
    float* outf = (float*)d_out;

    char* p = (char*)d_ws;
    auto alloc = [&](size_t bytes) {
        char* r = p;
        p += (bytes + 255) & ~(size_t)255;
        return r;
    };
    _Float16* WTl  = (_Float16*)alloc((size_t)1024 * 768 * 2);
    _Float16* WTg  = (_Float16*)alloc((size_t)384 * 384 * 2);
    _Float16* xc   = (_Float16*)alloc((size_t)Bsz * TT * 512 * 2);
    _Float16* h16A = (_Float16*)alloc((size_t)Bsz * 256 * 2);
    _Float16* h16B = (_Float16*)alloc((size_t)Bsz * 256 * 2);
    float*    cA   = (float*)alloc((size_t)Bsz * 256 * 4);
    float*    cB   = (float*)alloc((size_t)Bsz * 256 * 4);
    _Float16* g16A = (_Float16*)alloc((size_t)Bsz * 128 * 2);
    _Float16* g16B = (_Float16*)alloc((size_t)Bsz * 128 * 2);

    (void)hipFuncSetAttribute((const void*)step_fused,
                              hipFuncAttributeMaxDynamicSharedMemorySize, 131072);

    conv_all<<<Bsz * TT * 64 / 256, 256, 0, stream>>>(noise, xc);
    prep_lstm_w<<<1024 * 768 / 256, 256, 0, stream>>>(Wx_l, Wh_l, WTl);
    prep_gru_w<<<(384 * 384 + 255) / 256, 256, 0, stream>>>(Wx_g, Wh_g, WTg);

    _Float16* hb[2] = {h16A, h16B};   // h(s) in hb[s&1]
    float*    cb[2] = {cA, cB};
    _Float16* gh[2] = {g16A, g16B};   // g(tau) in gh[tau&1]

    for (int t = 0; t < TT; ++t) {
        const int wi = t & 1, ri = (t + 1) & 1;
        // GRU(t-1): reads h(t-1)=hb[ri], g(t-2)=gh[wi]; writes g(t-1)=gh[ri].
        step_fused<<<256, 512, 131072, stream>>>(
            xc + (size_t)t * Bsz * 512, WTl, b_l,
            hb[ri], cb[ri], hb[wi], cb[wi],
            WTg, b_in, b_rec, gh[wi], gh[ri],
            t == 0 ? 1 : 0, t >= 1 ? 1 : 0, t == 1 ? 1 : 0);
    }
    // GRU(9): reads h(9)=hb[1], g(8)=gh[0]; writes g(9)=gh[1]; then dense.
    gru_dense_tail<<<256, 512, 0, stream>>>(hb[1], gh[0], WTg, b_in, b_rec,
                                            gh[1], Wd, bd, outf);
}